// Round 1
// baseline (253.147 us; speedup 1.0000x reference)
//
#include <hip/hip_runtime.h>
#include <math.h>

typedef float f4 __attribute__((ext_vector_type(4)));

#define D      2048
#define NE     64
#define MB     64            // tokens per block
#define KB     64            // K chunk
#define NCH    (D / KB)      // 32
#define LSTR   68            // LDS row stride in floats (16B-aligned, conflict-light)

__global__ __launch_bounds__(256, 1)
void moe_gate_kernel(const float* __restrict__ x,
                     const float* __restrict__ W,
                     float* __restrict__ out,
                     int ntok)
{
    __shared__ float Xl[2][MB * LSTR];   // 2 * 17408 B
    __shared__ float Wl[2][NE * LSTR];   // 2 * 17408 B  -> 68 KB total

    const int t    = threadIdx.x;
    const int tok0 = blockIdx.x * MB;

    // compute mapping: 16 token-groups x 16 expert-groups, strided rows
    const int tg = t & 15;        // token group
    const int eg = t >> 4;        // expert group (0..15)

    // staging mapping: 4 rows/thread (rb, rb+16, rb+32, rb+48), 16B col per thread
    const int rb = t >> 4;        // 0..15
    const int c4 = t & 15;        // float4 column 0..15

    const float* xg = x + (size_t)(tok0 + rb) * D + (c4 << 2);
    const float* wg = W + (size_t)rb * D + (c4 << 2);

    f4 xr[4], wr[4];

    // ---- prologue: stage chunk 0 ----
#pragma unroll
    for (int p = 0; p < 4; ++p) {
        xr[p] = *(const f4*)(xg + (size_t)(p << 4) * D);
        wr[p] = *(const f4*)(wg + (size_t)(p << 4) * D);
    }
#pragma unroll
    for (int p = 0; p < 4; ++p) {
        *(f4*)&Xl[0][(rb + (p << 4)) * LSTR + (c4 << 2)] = xr[p];
        *(f4*)&Wl[0][(rb + (p << 4)) * LSTR + (c4 << 2)] = wr[p];
    }
    __syncthreads();

    float acc[4][4] = {{0.f, 0.f, 0.f, 0.f}};

    int cur = 0;
    for (int ch = 0; ch < NCH; ++ch) {
        // issue next chunk's global loads early (latency hides under FMAs)
        if (ch + 1 < NCH) {
            const float* xgc = xg + (ch + 1) * KB;
            const float* wgc = wg + (ch + 1) * KB;
#pragma unroll
            for (int p = 0; p < 4; ++p) {
                xr[p] = *(const f4*)(xgc + (size_t)(p << 4) * D);
                wr[p] = *(const f4*)(wgc + (size_t)(p << 4) * D);
            }
        }

        // compute on current buffer
        const float* Xb = Xl[cur];
        const float* Wb = Wl[cur];
#pragma unroll
        for (int q = 0; q < KB / 4; ++q) {
            f4 xf[4], wf[4];
#pragma unroll
            for (int i = 0; i < 4; ++i)
                xf[i] = *(const f4*)&Xb[(tg + (i << 4)) * LSTR + (q << 2)];
#pragma unroll
            for (int j = 0; j < 4; ++j)
                wf[j] = *(const f4*)&Wb[(eg + (j << 4)) * LSTR + (q << 2)];
#pragma unroll
            for (int i = 0; i < 4; ++i)
#pragma unroll
                for (int j = 0; j < 4; ++j) {
                    float s = acc[i][j];
                    s = fmaf(xf[i][0], wf[j][0], s);
                    s = fmaf(xf[i][1], wf[j][1], s);
                    s = fmaf(xf[i][2], wf[j][2], s);
                    s = fmaf(xf[i][3], wf[j][3], s);
                    acc[i][j] = s;
                }
        }

        // write next chunk into the other buffer (waitcnt auto-inserted on reg dep)
        if (ch + 1 < NCH) {
            const int nb = cur ^ 1;
#pragma unroll
            for (int p = 0; p < 4; ++p) {
                *(f4*)&Xl[nb][(rb + (p << 4)) * LSTR + (c4 << 2)] = xr[p];
                *(f4*)&Wl[nb][(rb + (p << 4)) * LSTR + (c4 << 2)] = wr[p];
            }
        }
        __syncthreads();
        cur ^= 1;
    }

    // ---- epilogue: per-token top-2 + softmax ----
    // alias C over Xl[0]: needs 64*65 = 4160 floats <= 4352 (fits in Xl[0] alone)
    float* Cl = &Xl[0][0];
#pragma unroll
    for (int i = 0; i < 4; ++i)
#pragma unroll
        for (int j = 0; j < 4; ++j)
            Cl[(tg + (i << 4)) * (NE + 1) + (eg + (j << 4))] = acc[i][j];
    __syncthreads();

    if (t < MB) {
        const float* row = &Cl[t * (NE + 1)];
        float m1 = -INFINITY, m2 = -INFINITY;
        int i1 = 0, i2 = 0;
#pragma unroll
        for (int e = 0; e < NE; ++e) {
            float v = row[e];
            // strict > keeps lowest index on ties, matching jax.lax.top_k
            if (v > m1)      { m2 = m1; i2 = i1; m1 = v; i1 = e; }
            else if (v > m2) { m2 = v;  i2 = e; }
        }
        const float p1 = 1.0f / (1.0f + expf(m2 - m1));  // stable: m2 <= m1
        const float p2 = 1.0f - p1;

        const int tok = tok0 + t;
        out[(size_t)tok * 2 + 0] = (float)i1;
        out[(size_t)tok * 2 + 1] = (float)i2;
        float* vals = out + (size_t)ntok * 2;
        vals[(size_t)tok * 2 + 0] = p1;
        vals[(size_t)tok * 2 + 1] = p2;
    }
}

extern "C" void kernel_launch(void* const* d_in, const int* in_sizes, int n_in,
                              void* d_out, int out_size, void* d_ws, size_t ws_size,
                              hipStream_t stream)
{
    const float* x = (const float*)d_in[0];
    const float* W = (const float*)d_in[1];
    float* out = (float*)d_out;
    const int ntok = in_sizes[0] / D;            // 16384
    const int grid = (ntok + MB - 1) / MB;       // 256
    moe_gate_kernel<<<grid, 256, 0, stream>>>(x, W, out, ntok);
}